// Round 1
// baseline (124.098 us; speedup 1.0000x reference)
//
#include <hip/hip_runtime.h>
#include <math.h>

#define EPSF 1e-5f
constexpr int NT  = 1024;
constexpr int ND  = 128;
constexpr int KIN = 19;
constexpr int H   = 256;
constexpr int L   = 128;

__global__ __launch_bounds__(256) void fused_net(
    const float* __restrict__ x0,
    const float* __restrict__ x,
    const int*   __restrict__ Nv,
    const float* __restrict__ basis,
    const float* __restrict__ v,
    const float* __restrict__ W0,
    const float* __restrict__ b0,
    const float* __restrict__ W1,
    const float* __restrict__ b1,
    const float* __restrict__ W2,
    const float* __restrict__ b2,
    float* __restrict__ out)
{
    const int g    = blockIdx.x;     // b*NT + t
    const int tid  = threadIdx.x;
    const int bidx = g >> 10;        // NT = 1024

    __shared__ __align__(16) float feat[ND][20];   // 19 feats + pad/zero
    __shared__ float red[ND][3];
    __shared__ float scal[13];
    __shared__ float hm[H];
    __shared__ float h1s[H];

    const float* xp = x + (size_t)g * (ND * 3);
    const float* vp = v + (size_t)g * (ND * 3);

    float vx=0.f, vy=0.f, vz=0.f, xx=0.f, xy=0.f, xz=0.f;
    if (tid < ND) {
        vx = vp[tid*3+0]; vy = vp[tid*3+1]; vz = vp[tid*3+2];
        xx = xp[tid*3+0]; xy = xp[tid*3+1]; xz = xp[tid*3+2];
        red[tid][0] = vx; red[tid][1] = vy; red[tid][2] = vz;
    }
    __syncthreads();
    // tree-reduce v over ND -> v0*ND in red[0][*]
    for (int s = ND/2; s > 0; s >>= 1) {
        if (tid < s) {
            red[tid][0] += red[tid+s][0];
            red[tid][1] += red[tid+s][1];
            red[tid][2] += red[tid+s][2];
        }
        __syncthreads();
    }
    if (tid == 0) {
        const float inv = 1.0f / (float)ND;
        float v0x = red[0][0]*inv, v0y = red[0][1]*inv, v0z = red[0][2]*inv;
        float ax = x0[g*3+0], ay = x0[g*3+1], az = x0[g*3+2];
        float x0n = sqrtf(ax*ax + ay*ay + az*az) + EPSF;
        float v0n = sqrtf(v0x*v0x + v0y*v0y + v0z*v0z) + EPSF;
        float ix  = 1.f / x0n, iv0 = 1.f / v0n;
        const float* bs = basis + bidx*9;
        scal[0] = log1pf((float)Nv[g]);
        scal[1] = x0n;
        scal[2] = (ax*bs[0] + ay*bs[1] + az*bs[2]) * ix;
        scal[3] = (ax*bs[3] + ay*bs[4] + az*bs[5]) * ix;
        scal[4] = (ax*bs[6] + ay*bs[7] + az*bs[8]) * ix;
        scal[5] = v0n;
        scal[6] = (v0x*bs[0] + v0y*bs[1] + v0z*bs[2]) * iv0;
        scal[7] = (v0x*bs[3] + v0y*bs[4] + v0z*bs[5]) * iv0;
        scal[8] = (v0x*bs[6] + v0y*bs[7] + v0z*bs[8]) * iv0;
        scal[9] = (ax*v0x + ay*v0y + az*v0z) * ix * iv0;
        scal[10] = v0x; scal[11] = v0y; scal[12] = v0z;
    }
    __syncthreads();
    if (tid < ND) {
        float cx = vx - scal[10], cy = vy - scal[11], cz = vz - scal[12];
        float xn = sqrtf(xx*xx + xy*xy + xz*xz) + EPSF;
        float vn = sqrtf(cx*cx + cy*cy + cz*cz) + EPSF;
        float ixn = 1.f/xn, ivn = 1.f/vn;
        const float* bs = basis + bidx*9;
        #pragma unroll
        for (int k = 0; k < 10; ++k) feat[tid][k] = scal[k];
        feat[tid][10] = xn;
        feat[tid][11] = (xx*bs[0] + xy*bs[1] + xz*bs[2]) * ixn;
        feat[tid][12] = (xx*bs[3] + xy*bs[4] + xz*bs[5]) * ixn;
        feat[tid][13] = (xx*bs[6] + xy*bs[7] + xz*bs[8]) * ixn;
        feat[tid][14] = vn;
        feat[tid][15] = (cx*bs[0] + cy*bs[1] + cz*bs[2]) * ivn;
        feat[tid][16] = (cx*bs[3] + cy*bs[4] + cz*bs[5]) * ivn;
        feat[tid][17] = (cx*bs[6] + cy*bs[7] + cz*bs[8]) * ivn;
        feat[tid][18] = (xx*cx + xy*cy + xz*cz) * ixn * ivn;
        feat[tid][19] = 0.f;
    }

    // W0 column for this thread's neuron (padded to 20 with zero)
    float w0c[20];
    #pragma unroll
    for (int k = 0; k < KIN; ++k) w0c[k] = W0[k*H + tid];
    w0c[19] = 0.f;
    const float b0c = b0[tid];
    __syncthreads();

    // Layer 0 + fused mean-pool over d
    float hs = 0.f;
    for (int d = 0; d < ND; ++d) {
        const float4* fr = reinterpret_cast<const float4*>(&feat[d][0]);
        float4 f0 = fr[0], f1 = fr[1], f2 = fr[2], f3 = fr[3], f4 = fr[4];
        float a = b0c;
        a = fmaf(f0.x, w0c[0],  a); a = fmaf(f0.y, w0c[1],  a);
        a = fmaf(f0.z, w0c[2],  a); a = fmaf(f0.w, w0c[3],  a);
        a = fmaf(f1.x, w0c[4],  a); a = fmaf(f1.y, w0c[5],  a);
        a = fmaf(f1.z, w0c[6],  a); a = fmaf(f1.w, w0c[7],  a);
        a = fmaf(f2.x, w0c[8],  a); a = fmaf(f2.y, w0c[9],  a);
        a = fmaf(f2.z, w0c[10], a); a = fmaf(f2.w, w0c[11], a);
        a = fmaf(f3.x, w0c[12], a); a = fmaf(f3.y, w0c[13], a);
        a = fmaf(f3.z, w0c[14], a); a = fmaf(f3.w, w0c[15], a);
        a = fmaf(f4.x, w0c[16], a); a = fmaf(f4.y, w0c[17], a);
        a = fmaf(f4.z, w0c[18], a);
        hs += (a > 0.f) ? a : 0.01f * a;
    }
    hm[tid] = hs * (1.0f / (float)ND);
    __syncthreads();

    // Layer 1
    {
        float acc = b1[tid];
        const float* w = W1 + tid;
        for (int k = 0; k < H; ++k) acc = fmaf(hm[k], w[(size_t)k*H], acc);
        h1s[tid] = (acc > 0.f) ? acc : 0.01f * acc;
    }
    __syncthreads();

    // Layer 2
    if (tid < L) {
        float acc = b2[tid];
        const float* w = W2 + tid;
        for (int k = 0; k < H; ++k) acc = fmaf(h1s[k], w[(size_t)k*L], acc);
        out[(size_t)g*L + tid] = acc;
    }
}

extern "C" void kernel_launch(void* const* d_in, const int* in_sizes, int n_in,
                              void* d_out, int out_size, void* d_ws, size_t ws_size,
                              hipStream_t stream) {
    const float* x0    = (const float*)d_in[0];
    const float* x     = (const float*)d_in[1];
    const int*   Nv    = (const int*)  d_in[2];
    const float* basis = (const float*)d_in[3];
    const float* v     = (const float*)d_in[4];
    const float* W0    = (const float*)d_in[5];
    const float* b0    = (const float*)d_in[6];
    const float* W1    = (const float*)d_in[7];
    const float* b1    = (const float*)d_in[8];
    const float* W2    = (const float*)d_in[9];
    const float* b2    = (const float*)d_in[10];
    float* out = (float*)d_out;

    dim3 grid(4 * NT);
    dim3 block(256);
    hipLaunchKernelGGL(fused_net, grid, block, 0, stream,
                       x0, x, Nv, basis, v, W0, b0, W1, b1, W2, b2, out);
}

// Round 2
// 62.460 us; speedup vs baseline: 1.9869x; 1.9869x over previous
//
#include <hip/hip_runtime.h>
#include <math.h>

#define EPSF 1e-5f
constexpr int NT  = 1024;
constexpr int ND  = 128;
constexpr int KIN = 19;
constexpr int H   = 256;
constexpr int L   = 128;

typedef __attribute__((ext_vector_type(8))) short short8;
typedef __attribute__((ext_vector_type(4))) float f32x4;

static __device__ inline ushort f2bf(float f) {
    // round-to-nearest-even fp32 -> bf16 (no NaN inputs here)
    unsigned u = __float_as_uint(f);
    unsigned r = (u + 0x7fffu + ((u >> 16) & 1u)) >> 16;
    return (ushort)r;
}

// Kernel A: features + bf16 MFMA layer0 + leaky + mean-pool -> hm[4096][256] in ws
__global__ __launch_bounds__(256) void k_feat_l0(
    const float* __restrict__ x0, const float* __restrict__ x,
    const int*   __restrict__ Nv, const float* __restrict__ basis,
    const float* __restrict__ v,  const float* __restrict__ W0,
    const float* __restrict__ b0, float* __restrict__ hm_out)
{
    const int g    = blockIdx.x;          // b*NT + t
    const int tid  = threadIdx.x;
    const int lane = tid & 63;
    const int wave = tid >> 6;
    const int bidx = g >> 10;

    // A-fragments pre-arranged: featb[mt][lane][j] (mt=M-tile 0..7)
    __shared__ ushort featb[8 * 64 * 8];          // 8 KB
    __shared__ float red[ND][3];
    __shared__ float scal[13];

    const float* xp = x + (size_t)g * (ND * 3);
    const float* vp = v + (size_t)g * (ND * 3);

    // ---- B fragments (W0 bf16) + bias C-in, built from L2-resident W0 ----
    short8 bfrag[4];
    f32x4  cb[4];
    {
        const int col16 = lane & 15;
        const int kb    = lane >> 4;
        #pragma unroll
        for (int nt = 0; nt < 4; ++nt) {
            const int ntg = wave * 4 + nt;
            const int col = ntg * 16 + col16;
            short8 bv;
            #pragma unroll
            for (int j = 0; j < 8; ++j) {
                const int k = kb * 8 + j;
                float val = (k < KIN) ? W0[k * H + col] : 0.f;
                bv[j] = (short)f2bf(val);
            }
            bfrag[nt] = bv;
            const float bb = b0[col];
            #pragma unroll
            for (int r = 0; r < 4; ++r) cb[nt][r] = bb;
        }
    }

    // ---- feature computation ----
    float vx=0.f, vy=0.f, vz=0.f, xx=0.f, xy=0.f, xz=0.f;
    if (tid < ND) {
        vx = vp[tid*3+0]; vy = vp[tid*3+1]; vz = vp[tid*3+2];
        xx = xp[tid*3+0]; xy = xp[tid*3+1]; xz = xp[tid*3+2];
        red[tid][0] = vx; red[tid][1] = vy; red[tid][2] = vz;
    }
    __syncthreads();
    for (int s = ND/2; s > 0; s >>= 1) {
        if (tid < s) {
            red[tid][0] += red[tid+s][0];
            red[tid][1] += red[tid+s][1];
            red[tid][2] += red[tid+s][2];
        }
        __syncthreads();
    }
    if (tid == 0) {
        const float inv = 1.0f / (float)ND;
        float v0x = red[0][0]*inv, v0y = red[0][1]*inv, v0z = red[0][2]*inv;
        float ax = x0[g*3+0], ay = x0[g*3+1], az = x0[g*3+2];
        float x0n = sqrtf(ax*ax + ay*ay + az*az) + EPSF;
        float v0n = sqrtf(v0x*v0x + v0y*v0y + v0z*v0z) + EPSF;
        float ix  = 1.f / x0n, iv0 = 1.f / v0n;
        const float* bs = basis + bidx*9;
        scal[0] = log1pf((float)Nv[g]);
        scal[1] = x0n;
        scal[2] = (ax*bs[0] + ay*bs[1] + az*bs[2]) * ix;
        scal[3] = (ax*bs[3] + ay*bs[4] + az*bs[5]) * ix;
        scal[4] = (ax*bs[6] + ay*bs[7] + az*bs[8]) * ix;
        scal[5] = v0n;
        scal[6] = (v0x*bs[0] + v0y*bs[1] + v0z*bs[2]) * iv0;
        scal[7] = (v0x*bs[3] + v0y*bs[4] + v0z*bs[5]) * iv0;
        scal[8] = (v0x*bs[6] + v0y*bs[7] + v0z*bs[8]) * iv0;
        scal[9] = (ax*v0x + ay*v0y + az*v0z) * ix * iv0;
        scal[10] = v0x; scal[11] = v0y; scal[12] = v0z;
    }
    __syncthreads();
    if (tid < ND) {
        float cx = vx - scal[10], cy = vy - scal[11], cz = vz - scal[12];
        float xn = sqrtf(xx*xx + xy*xy + xz*xz) + EPSF;
        float vn = sqrtf(cx*cx + cy*cy + cz*cz) + EPSF;
        float ixn = 1.f/xn, ivn = 1.f/vn;
        const float* bs = basis + bidx*9;
        float f[32];
        #pragma unroll
        for (int k = 0; k < 10; ++k) f[k] = scal[k];
        f[10] = xn;
        f[11] = (xx*bs[0] + xy*bs[1] + xz*bs[2]) * ixn;
        f[12] = (xx*bs[3] + xy*bs[4] + xz*bs[5]) * ixn;
        f[13] = (xx*bs[6] + xy*bs[7] + xz*bs[8]) * ixn;
        f[14] = vn;
        f[15] = (cx*bs[0] + cy*bs[1] + cz*bs[2]) * ivn;
        f[16] = (cx*bs[3] + cy*bs[4] + cz*bs[5]) * ivn;
        f[17] = (cx*bs[6] + cy*bs[7] + cz*bs[8]) * ivn;
        f[18] = (xx*cx + xy*cy + xz*cz) * ixn * ivn;
        #pragma unroll
        for (int k = KIN; k < 32; ++k) f[k] = 0.f;
        // write in A-fragment order: row d = mt*16 + r16; lane = kb*16 + r16
        const int mt  = tid >> 4;
        const int r16 = tid & 15;
        #pragma unroll
        for (int kb2 = 0; kb2 < 4; ++kb2) {
            short8 c;
            #pragma unroll
            for (int j = 0; j < 8; ++j) c[j] = (short)f2bf(f[kb2*8 + j]);
            *reinterpret_cast<short8*>(&featb[(mt*64 + kb2*16 + r16) * 8]) = c;
        }
    }
    __syncthreads();

    // ---- MFMA layer0: D = S(128x32) @ W0(32x256), fused leaky + row-pool ----
    f32x4 psum[4];
    #pragma unroll
    for (int nt = 0; nt < 4; ++nt)
        #pragma unroll
        for (int r = 0; r < 4; ++r) psum[nt][r] = 0.f;

    for (int mt = 0; mt < 8; ++mt) {
        const short8 af = *reinterpret_cast<const short8*>(&featb[(mt*64 + lane) * 8]);
        #pragma unroll
        for (int nt = 0; nt < 4; ++nt) {
            f32x4 d = __builtin_amdgcn_mfma_f32_16x16x32_bf16(af, bfrag[nt], cb[nt], 0, 0, 0);
            #pragma unroll
            for (int r = 0; r < 4; ++r) {
                float a = d[r];
                psum[nt][r] += (a > 0.f) ? a : 0.01f * a;
            }
        }
    }
    // column-sum: regs (4 rows) already summed below; reduce across lane-groups
    #pragma unroll
    for (int nt = 0; nt < 4; ++nt) {
        float s4 = psum[nt][0] + psum[nt][1] + psum[nt][2] + psum[nt][3];
        s4 += __shfl_xor(s4, 16, 64);
        s4 += __shfl_xor(s4, 32, 64);
        if (lane < 16)
            hm_out[(size_t)g * H + wave*64 + nt*16 + lane] = s4 * (1.0f / (float)ND);
    }
}

// Kernel B: layers 1-2, 8 t per block to amortize W1/W2 L2 traffic
__global__ __launch_bounds__(256) void k_l12(
    const float* __restrict__ hm, const float* __restrict__ W1,
    const float* __restrict__ b1, const float* __restrict__ W2,
    const float* __restrict__ b2, float* __restrict__ out)
{
    const int tb  = blockIdx.x * 8;
    const int tid = threadIdx.x;
    __shared__ float hs[8][H];   // 8 KB
    __shared__ float h1[8][H];   // 8 KB

    {   // cooperative load of 8 hm rows (coalesced float4)
        const float4* src = reinterpret_cast<const float4*>(hm + (size_t)tb * H);
        float4* dst = reinterpret_cast<float4*>(&hs[0][0]);
        #pragma unroll
        for (int i = 0; i < 2; ++i) dst[tid + i*256] = src[tid + i*256];
    }
    __syncthreads();

    {   // layer 1: thread owns neuron tid for all 8 t's
        float acc[8];
        const float bb = b1[tid];
        #pragma unroll
        for (int t = 0; t < 8; ++t) acc[t] = bb;
        for (int k = 0; k < H; ++k) {
            const float w = W1[(size_t)k * H + tid];
            #pragma unroll
            for (int t = 0; t < 8; ++t) acc[t] = fmaf(hs[t][k], w, acc[t]);
        }
        #pragma unroll
        for (int t = 0; t < 8; ++t) {
            float a = acc[t];
            h1[t][tid] = (a > 0.f) ? a : 0.01f * a;
        }
    }
    __syncthreads();

    {   // layer 2: threads 0-127 -> t 0..3, threads 128-255 -> t 4..7
        const int n  = tid & 127;
        const int t0 = (tid >> 7) * 4;
        float acc[4];
        const float bb = b2[n];
        #pragma unroll
        for (int t = 0; t < 4; ++t) acc[t] = bb;
        for (int k = 0; k < H; ++k) {
            const float w = W2[(size_t)k * L + n];
            #pragma unroll
            for (int t = 0; t < 4; ++t) acc[t] = fmaf(h1[t0 + t][k], w, acc[t]);
        }
        #pragma unroll
        for (int t = 0; t < 4; ++t)
            out[(size_t)(tb + t0 + t) * L + n] = acc[t];
    }
}

extern "C" void kernel_launch(void* const* d_in, const int* in_sizes, int n_in,
                              void* d_out, int out_size, void* d_ws, size_t ws_size,
                              hipStream_t stream) {
    const float* x0    = (const float*)d_in[0];
    const float* x     = (const float*)d_in[1];
    const int*   Nv    = (const int*)  d_in[2];
    const float* basis = (const float*)d_in[3];
    const float* v     = (const float*)d_in[4];
    const float* W0    = (const float*)d_in[5];
    const float* b0    = (const float*)d_in[6];
    const float* W1    = (const float*)d_in[7];
    const float* b1    = (const float*)d_in[8];
    const float* W2    = (const float*)d_in[9];
    const float* b2    = (const float*)d_in[10];
    float* out = (float*)d_out;
    float* hm  = (float*)d_ws;          // 4096*256*4 = 4 MB

    hipLaunchKernelGGL(k_feat_l0, dim3(4 * NT), dim3(256), 0, stream,
                       x0, x, Nv, basis, v, W0, b0, hm);
    hipLaunchKernelGGL(k_l12, dim3(4 * NT / 8), dim3(256), 0, stream,
                       hm, W1, b1, W2, b2, out);
}